// Round 1
// baseline (427.848 us; speedup 1.0000x reference)
//
#include <hip/hip_runtime.h>

#define EPW 64            // events per wave (= wave size, one preload per lane)
#define WAVES_PER_BLOCK 4 // 256 threads

__global__ __launch_bounds__(256) void spspmm_seg_kernel(
    const float* __restrict__ Aval,   // [NNZ_A, 64]
    const float* __restrict__ Bval,   // [NNZ_B]
    const int*   __restrict__ acd0,   // [M] sorted target idx
    const int*   __restrict__ acd1,   // [M] A row idx
    const int*   __restrict__ acd2,   // [M] B idx
    float*       __restrict__ out,    // [TAR_NNZ, 64]
    int M)
{
    const int lane = threadIdx.x & 63;
    const long wave_id = (long)blockIdx.x * WAVES_PER_BLOCK + (threadIdx.x >> 6);
    const long m0 = wave_id * EPW;
    if (m0 >= M) return;
    const int n = (int)min((long)EPW, (long)M - m0);

    // Per-lane preload of one event descriptor (coalesced).
    int   t_i = 0, a_i = 0;
    float bv_i = 0.f;
    if (lane < n) {
        t_i  = acd0[m0 + lane];
        a_i  = acd1[m0 + lane];
        bv_i = Bval[acd2[m0 + lane]];
    }

    float acc   = 0.f;
    int   cur_t = __shfl(t_i, 0);

    if (n == EPW) {
        #pragma unroll 8
        for (int e = 0; e < EPW; ++e) {
            const int   t  = __shfl(t_i, e);
            const int   a  = __shfl(a_i, e);
            const float bv = __shfl(bv_i, e);
            if (t != cur_t) {               // wave-uniform branch
                atomicAdd(&out[(long)cur_t * 64 + lane], acc);
                acc   = 0.f;
                cur_t = t;
            }
            acc = fmaf(Aval[(long)a * 64 + lane], bv, acc);
        }
    } else {
        for (int e = 0; e < n; ++e) {
            const int   t  = __shfl(t_i, e);
            const int   a  = __shfl(a_i, e);
            const float bv = __shfl(bv_i, e);
            if (t != cur_t) {
                atomicAdd(&out[(long)cur_t * 64 + lane], acc);
                acc   = 0.f;
                cur_t = t;
            }
            acc = fmaf(Aval[(long)a * 64 + lane], bv, acc);
        }
    }
    atomicAdd(&out[(long)cur_t * 64 + lane], acc);
}

extern "C" void kernel_launch(void* const* d_in, const int* in_sizes, int n_in,
                              void* d_out, int out_size, void* d_ws, size_t ws_size,
                              hipStream_t stream) {
    const float* Aval = (const float*)d_in[0];
    const float* Bval = (const float*)d_in[1];
    const int*   acd0 = (const int*)d_in[2];
    const int*   acd1 = (const int*)d_in[3];
    const int*   acd2 = (const int*)d_in[4];
    float* out = (float*)d_out;
    const int M = in_sizes[2];

    // Replays don't re-poison: zero the output inside the captured work.
    hipMemsetAsync(d_out, 0, (size_t)out_size * sizeof(float), stream);

    const long waves  = ((long)M + EPW - 1) / EPW;
    const long blocks = (waves + WAVES_PER_BLOCK - 1) / WAVES_PER_BLOCK;
    spspmm_seg_kernel<<<dim3((unsigned)blocks), dim3(WAVES_PER_BLOCK * 64), 0, stream>>>(
        Aval, Bval, acd0, acd1, acd2, out, M);
}

// Round 2
// 354.522 us; speedup vs baseline: 1.2068x; 1.2068x over previous
//
#include <hip/hip_runtime.h>

#define EPW 64            // events per wave
#define CH  16            // chunk: loads batched this deep (MLP)
#define WAVES_PER_BLOCK 4 // 256 threads

__global__ __launch_bounds__(256) void spspmm_seg_kernel(
    const float* __restrict__ Aval,   // [NNZ_A, 64]
    const float* __restrict__ Bval,   // [NNZ_B]
    const int*   __restrict__ acd0,   // [M] sorted target idx
    const int*   __restrict__ acd1,   // [M] A row idx
    const int*   __restrict__ acd2,   // [M] B idx
    float*       __restrict__ out,    // [TAR_NNZ, 64]
    int M)
{
    const int lane = threadIdx.x & 63;
    const int wid  = blockIdx.x * WAVES_PER_BLOCK + (threadIdx.x >> 6);
    const int m0   = wid * EPW;
    if (m0 >= M) return;
    const int mEnd = min(m0 + EPW, M);

    // Wave-exclusive ownership test: targets strictly inside (t_first, t_last)
    // have ALL their events inside this wave (acd0 sorted) -> plain store.
    const int t_first = acd0[m0];
    const int t_last  = acd0[mEnd - 1];

    float acc   = 0.f;
    int   cur_t = t_first;

    if (mEnd - m0 == EPW) {
        #pragma unroll 1
        for (int c = 0; c < EPW / CH; ++c) {
            const int mb = m0 + c * CH;
            // 1) descriptor chunk (wave-uniform addresses -> broadcast loads)
            int tt[CH], aa[CH]; float bb[CH];
            #pragma unroll
            for (int j = 0; j < CH; ++j) {
                tt[j] = acd0[mb + j];
                aa[j] = acd1[mb + j];
                bb[j] = Bval[acd2[mb + j]];
            }
            // 2) 16 independent A-row loads, nothing between them
            float v[CH];
            #pragma unroll
            for (int j = 0; j < CH; ++j)
                v[j] = Aval[(size_t)aa[j] * 64 + lane];
            // 3) segment scan on registers
            #pragma unroll
            for (int j = 0; j < CH; ++j) {
                if (tt[j] != cur_t) {                  // wave-uniform branch
                    float* p = out + (size_t)cur_t * 64 + lane;
                    if (cur_t == t_first) atomicAdd(p, acc);  // boundary
                    else                  *p = acc;           // exclusive
                    acc   = 0.f;
                    cur_t = tt[j];
                }
                acc = fmaf(v[j], bb[j], acc);
            }
        }
    } else {
        // tail wave (not hit for M % EPW == 0, kept for safety)
        for (int m = m0; m < mEnd; ++m) {
            const int   t  = acd0[m];
            const float bv = Bval[acd2[m]];
            const float av = Aval[(size_t)acd1[m] * 64 + lane];
            if (t != cur_t) {
                float* p = out + (size_t)cur_t * 64 + lane;
                if (cur_t == t_first) atomicAdd(p, acc);
                else                  *p = acc;
                acc = 0.f; cur_t = t;
            }
            acc = fmaf(av, bv, acc);
        }
    }
    // final segment ends at t_last -> may continue in next wave -> atomic
    atomicAdd(out + (size_t)cur_t * 64 + lane, acc);
}

extern "C" void kernel_launch(void* const* d_in, const int* in_sizes, int n_in,
                              void* d_out, int out_size, void* d_ws, size_t ws_size,
                              hipStream_t stream) {
    const float* Aval = (const float*)d_in[0];
    const float* Bval = (const float*)d_in[1];
    const int*   acd0 = (const int*)d_in[2];
    const int*   acd1 = (const int*)d_in[3];
    const int*   acd2 = (const int*)d_in[4];
    float* out = (float*)d_out;
    const int M = in_sizes[2];

    // Replays don't re-poison: zero output inside the captured work.
    hipMemsetAsync(d_out, 0, (size_t)out_size * sizeof(float), stream);

    const long waves  = ((long)M + EPW - 1) / EPW;
    const long blocks = (waves + WAVES_PER_BLOCK - 1) / WAVES_PER_BLOCK;
    spspmm_seg_kernel<<<dim3((unsigned)blocks), dim3(WAVES_PER_BLOCK * 64), 0, stream>>>(
        Aval, Bval, acd0, acd1, acd2, out, M);
}

// Round 3
// 289.555 us; speedup vs baseline: 1.4776x; 1.2244x over previous
//
#include <hip/hip_runtime.h>

#define EPW 64            // events per wave
#define CH  16            // A-row loads batched this deep
#define WPB 4             // waves per block (256 threads)

// Zero exactly the rows that receive atomicAdd flushes: the first/last target
// of every wave's event range. One 64-lane wave zeros one 256B row.
__global__ __launch_bounds__(256) void prezero_kernel(
    const int* __restrict__ acd0, float* __restrict__ out, int nwaves, int M)
{
    const int task = blockIdx.x * WPB + (threadIdx.x >> 6);
    const int lane = threadIdx.x & 63;
    if (task >= 2 * nwaves) return;
    const int w = task >> 1;
    int m = w * EPW + ((task & 1) ? (EPW - 1) : 0);
    if (m >= M) m = M - 1;
    const int t = acd0[m];
    out[(size_t)t * 64 + lane] = 0.f;
}

__global__ __launch_bounds__(256, 4) void spspmm_seg_kernel(
    const float* __restrict__ Aval,   // [NNZ_A, 64]
    const float* __restrict__ Bval,   // [NNZ_B]
    const int*   __restrict__ acd0,   // [M] sorted target idx
    const int*   __restrict__ acd1,   // [M] A row idx
    const int*   __restrict__ acd2,   // [M] B idx
    float*       __restrict__ out,    // [TAR, 64]
    int M, int TAR)
{
    const int lane = threadIdx.x & 63;
    const int wid  = blockIdx.x * WPB + (threadIdx.x >> 6);
    const int m0   = wid * EPW;
    if (m0 >= M) return;
    const int mEnd = min(m0 + EPW, M);

    const int t_first = __builtin_nontemporal_load(acd0 + m0);
    // Leading gap: targets with no events between prev wave's last target and ours.
    const int t_prev  = (m0 > 0) ? __builtin_nontemporal_load(acd0 + m0 - 1) : -1;
    for (int g = t_prev + 1; g < t_first; ++g)
        __builtin_nontemporal_store(0.f, out + (size_t)g * 64 + lane);

    float acc   = 0.f;
    int   cur_t = t_first;

    if (mEnd - m0 == EPW) {
        #pragma unroll 1
        for (int c = 0; c < EPW / CH; ++c) {
            const int mb = m0 + c * CH;
            // 1) descriptor chunk (streamed once -> nontemporal)
            int tt[CH], aa[CH]; float bb[CH];
            #pragma unroll
            for (int j = 0; j < CH; ++j) {
                tt[j] = __builtin_nontemporal_load(acd0 + mb + j);
                aa[j] = __builtin_nontemporal_load(acd1 + mb + j);
                bb[j] = Bval[__builtin_nontemporal_load(acd2 + mb + j)];
            }
            // 2) 16 independent A-row gathers, kept in flight (128-VGPR budget)
            float v[CH];
            #pragma unroll
            for (int j = 0; j < CH; ++j)
                v[j] = Aval[(size_t)aa[j] * 64 + lane];
            // 3) segment scan on registers
            #pragma unroll
            for (int j = 0; j < CH; ++j) {
                const int t = tt[j];
                if (t != cur_t) {                    // wave-uniform branch
                    float* p = out + (size_t)cur_t * 64 + lane;
                    if (cur_t == t_first) atomicAdd(p, acc);          // boundary
                    else __builtin_nontemporal_store(acc, p);         // exclusive
                    for (int g = cur_t + 1; g < t; ++g)               // interior gap
                        __builtin_nontemporal_store(0.f, out + (size_t)g * 64 + lane);
                    acc   = 0.f;
                    cur_t = t;
                }
                acc = fmaf(v[j], bb[j], acc);
            }
        }
    } else {
        // tail wave (not hit when M % EPW == 0)
        for (int m = m0; m < mEnd; ++m) {
            const int   t  = acd0[m];
            const float bv = Bval[acd2[m]];
            const float av = Aval[(size_t)acd1[m] * 64 + lane];
            if (t != cur_t) {
                float* p = out + (size_t)cur_t * 64 + lane;
                if (cur_t == t_first) atomicAdd(p, acc);
                else __builtin_nontemporal_store(acc, p);
                for (int g = cur_t + 1; g < t; ++g)
                    __builtin_nontemporal_store(0.f, out + (size_t)g * 64 + lane);
                acc = 0.f; cur_t = t;
            }
            acc = fmaf(av, bv, acc);
        }
    }
    // Final segment may continue into the next wave -> atomic (row pre-zeroed).
    atomicAdd(out + (size_t)cur_t * 64 + lane, acc);

    // Trailing gap after the very last event's target.
    if (mEnd == M) {
        const int tl = acd0[M - 1];
        for (int g = tl + 1; g < TAR; ++g)
            __builtin_nontemporal_store(0.f, out + (size_t)g * 64 + lane);
    }
}

extern "C" void kernel_launch(void* const* d_in, const int* in_sizes, int n_in,
                              void* d_out, int out_size, void* d_ws, size_t ws_size,
                              hipStream_t stream) {
    const float* Aval = (const float*)d_in[0];
    const float* Bval = (const float*)d_in[1];
    const int*   acd0 = (const int*)d_in[2];
    const int*   acd1 = (const int*)d_in[3];
    const int*   acd2 = (const int*)d_in[4];
    float* out = (float*)d_out;
    const int M   = in_sizes[2];
    const int TAR = out_size / 64;

    const int nwaves = (M + EPW - 1) / EPW;

    // Pre-zero only the atomic-target rows (~33 MB instead of 256 MB memset).
    {
        const int tasks  = 2 * nwaves;
        const int blocks = (tasks + WPB - 1) / WPB;
        prezero_kernel<<<dim3(blocks), dim3(WPB * 64), 0, stream>>>(acd0, out, nwaves, M);
    }

    const int blocks = (nwaves + WPB - 1) / WPB;
    spspmm_seg_kernel<<<dim3(blocks), dim3(WPB * 64), 0, stream>>>(
        Aval, Bval, acd0, acd1, acd2, out, M, TAR);
}